// Round 1
// baseline (464.966 us; speedup 1.0000x reference)
//
#include <hip/hip_runtime.h>

// Scatter-mean, three-tier strategy by workspace size:
//
//  Tier P (ws >= ~257MB): counting-sort permute + streaming segmented reduce.
//    The edge->node map is random, so node-major processing implies
//    edge-random 512B READS (measured ~0.7 TB/s effective in the gather
//    baseline, 393.6us). Instead: stream msg sequentially at full BW and
//    pay the randomness as 512B WRITES (latency-tolerant, write-combined),
//    then reduce node-major segments with fully contiguous reads.
//      count -> exclusive scan (3 tiny kernels) -> permute -> reduce
//    Predicted ~200-260us.
//
//  Tier G (ws >= ~13MB): previous verified bucket-gather baseline (393.6us).
//  Tier A: atomic fallback.
//
// E=500000, D=128, N=50000.

#define D_DIM 128
#define DV    32     // float4 chunks per row
#define CAP   64

// ===================== Tier P kernels =====================

__global__ void count_kernel(const int* __restrict__ index,
                             int* __restrict__ counts, int E) {
    int e = blockIdx.x * blockDim.x + threadIdx.x;
    if (e < E) atomicAdd(&counts[index[e]], 1);
}

// Per-block Hillis-Steele inclusive scan; emits per-element exclusive
// (within block) prefix and the block total.
__global__ void scan_blocks_kernel(const int* __restrict__ counts,
                                   int* __restrict__ base,
                                   int* __restrict__ blocksum, int N) {
    __shared__ int s[256];
    int tid = threadIdx.x;
    int i = blockIdx.x * 256 + tid;
    int v = (i < N) ? counts[i] : 0;
    s[tid] = v;
    __syncthreads();
    for (int d = 1; d < 256; d <<= 1) {
        int t = (tid >= d) ? s[tid - d] : 0;
        __syncthreads();
        s[tid] += t;
        __syncthreads();
    }
    if (i < N) base[i] = s[tid] - v;          // exclusive within block
    if (tid == 255) blocksum[blockIdx.x] = s[255];
}

__global__ void scan_sums_kernel(int* __restrict__ blocksum, int nb) {
    __shared__ int s[256];
    int tid = threadIdx.x;
    int v = (tid < nb) ? blocksum[tid] : 0;
    s[tid] = v;
    __syncthreads();
    for (int d = 1; d < 256; d <<= 1) {
        int t = (tid >= d) ? s[tid - d] : 0;
        __syncthreads();
        s[tid] += t;
        __syncthreads();
    }
    if (tid < nb) blocksum[tid] = s[tid] - v; // exclusive block offsets
}

__global__ void scan_add_kernel(int* __restrict__ base,
                                const int* __restrict__ blocksum, int N) {
    int i = blockIdx.x * blockDim.x + threadIdx.x;
    if (i < N) base[i] += blocksum[i >> 8];
}

// One half-wave (32 lanes x float4 = 512B) per edge row, grid-strided.
// Sequential msg read; random 512B write into node-major order.
__global__ __launch_bounds__(256)
void permute_kernel(const float* __restrict__ msg,
                    const int* __restrict__ index,
                    const int* __restrict__ base,
                    int* __restrict__ off,
                    float* __restrict__ sorted, int E) {
    int tid = blockIdx.x * blockDim.x + threadIdx.x;
    int half_id = tid >> 5;
    int sub  = threadIdx.x & 31;
    int lane = threadIdx.x & 63;
    int nhalves = (gridDim.x * blockDim.x) >> 5;
    const float4* m4 = reinterpret_cast<const float4*>(msg);
    float4* s4 = reinterpret_cast<float4*>(sorted);
    for (int e = half_id; e < E; e += nhalves) {
        int dst = 0;
        if (sub == 0) {
            int idx = index[e];
            dst = base[idx] + atomicAdd(&off[idx], 1);
        }
        dst = __shfl(dst, lane & 32);         // broadcast from lane 0 / 32
        float4 v = m4[(size_t)e * DV + sub];
        s4[(size_t)dst * DV + sub] = v;
    }
}

// One wave per node; rows [base[n], base[n]+cnt) are contiguous, so every
// vmem instruction reads a contiguous 1KB (rows j+2k and j+2k+1).
__global__ __launch_bounds__(256)
void reduce_kernel(const float* __restrict__ sorted,
                   const int* __restrict__ counts,
                   const int* __restrict__ base,
                   float* __restrict__ out, int N) {
    int gtid = blockIdx.x * blockDim.x + threadIdx.x;
    int node = gtid >> 6;
    if (node >= N) return;
    int lane = threadIdx.x & 63;
    int half = lane >> 5;
    int sub  = lane & 31;

    int cnt   = counts[node];
    int start = base[node];

    const float4* s4 = reinterpret_cast<const float4*>(sorted);
    float4 acc = make_float4(0.0f, 0.0f, 0.0f, 0.0f);

    int last = cnt - 1;
    for (int j = 0; j < cnt; j += 8) {
        int i0 = j + 0 + half, i1 = j + 2 + half, i2 = j + 4 + half, i3 = j + 6 + half;
        int r0 = start + (i0 < cnt ? i0 : last);
        int r1 = start + (i1 < cnt ? i1 : last);
        int r2 = start + (i2 < cnt ? i2 : last);
        int r3 = start + (i3 < cnt ? i3 : last);
        float4 v0 = s4[(size_t)r0 * DV + sub];
        float4 v1 = s4[(size_t)r1 * DV + sub];
        float4 v2 = s4[(size_t)r2 * DV + sub];
        float4 v3 = s4[(size_t)r3 * DV + sub];
        if (i0 < cnt) { acc.x += v0.x; acc.y += v0.y; acc.z += v0.z; acc.w += v0.w; }
        if (i1 < cnt) { acc.x += v1.x; acc.y += v1.y; acc.z += v1.z; acc.w += v1.w; }
        if (i2 < cnt) { acc.x += v2.x; acc.y += v2.y; acc.z += v2.z; acc.w += v2.w; }
        if (i3 < cnt) { acc.x += v3.x; acc.y += v3.y; acc.z += v3.z; acc.w += v3.w; }
    }

    acc.x += __shfl_xor(acc.x, 32);
    acc.y += __shfl_xor(acc.y, 32);
    acc.z += __shfl_xor(acc.z, 32);
    acc.w += __shfl_xor(acc.w, 32);

    float inv = 1.0f / fmaxf((float)cnt, 1.0f);
    acc.x *= inv; acc.y *= inv; acc.z *= inv; acc.w *= inv;

    if (half == 0) {
        reinterpret_cast<float4*>(out)[(size_t)node * DV + sub] = acc;
    }
}

// ===================== Tier G: verified bucket-gather baseline =====================

__global__ void bucket_kernel(const int* __restrict__ index,
                              int* __restrict__ cursor,
                              int* __restrict__ bucket,
                              int E) {
    int e = blockIdx.x * blockDim.x + threadIdx.x;
    if (e >= E) return;
    int idx = index[e];
    int pos = atomicAdd(&cursor[idx], 1);
    if (pos < CAP) bucket[(size_t)idx * CAP + pos] = e;
}

__global__ __launch_bounds__(256, 8)
void gather_kernel(const float* __restrict__ msg,
                   const int* __restrict__ cursor,
                   const int* __restrict__ bucket,
                   float* __restrict__ out,
                   int N) {
    int gtid = blockIdx.x * blockDim.x + threadIdx.x;
    int node = gtid >> 6;
    if (node >= N) return;
    int lane = threadIdx.x & 63;
    int half = lane >> 5;
    int sub  = lane & 31;

    int cnt_true = cursor[node];
    int cnt = cnt_true < CAP ? cnt_true : CAP;

    int eid = (lane < cnt) ? bucket[(size_t)node * CAP + lane] : 0;

    const float4* m4 = reinterpret_cast<const float4*>(msg);
    float4 acc = make_float4(0.0f, 0.0f, 0.0f, 0.0f);

    for (int j = 0; j < cnt; j += 8) {
        int i0 = j + 0 + half, i1 = j + 2 + half, i2 = j + 4 + half, i3 = j + 6 + half;
        int e0 = __shfl(eid, i0);
        int e1 = __shfl(eid, i1);
        int e2 = __shfl(eid, i2);
        int e3 = __shfl(eid, i3);
        float4 v0 = m4[(size_t)e0 * 32 + sub];
        float4 v1 = m4[(size_t)e1 * 32 + sub];
        float4 v2 = m4[(size_t)e2 * 32 + sub];
        float4 v3 = m4[(size_t)e3 * 32 + sub];
        if (i0 < cnt) { acc.x += v0.x; acc.y += v0.y; acc.z += v0.z; acc.w += v0.w; }
        if (i1 < cnt) { acc.x += v1.x; acc.y += v1.y; acc.z += v1.z; acc.w += v1.w; }
        if (i2 < cnt) { acc.x += v2.x; acc.y += v2.y; acc.z += v2.z; acc.w += v2.w; }
        if (i3 < cnt) { acc.x += v3.x; acc.y += v3.y; acc.z += v3.z; acc.w += v3.w; }
    }

    acc.x += __shfl_xor(acc.x, 32);
    acc.y += __shfl_xor(acc.y, 32);
    acc.z += __shfl_xor(acc.z, 32);
    acc.w += __shfl_xor(acc.w, 32);

    float inv = 1.0f / fmaxf((float)cnt_true, 1.0f);
    acc.x *= inv; acc.y *= inv; acc.z *= inv; acc.w *= inv;

    if (half == 0) {
        reinterpret_cast<float4*>(out)[(size_t)node * 32 + sub] = acc;
    }
}

// ===================== Tier A: atomic fallback =====================

__global__ void scatter_add_kernel(const float* __restrict__ msg,
                                   const int* __restrict__ index,
                                   float* __restrict__ out,
                                   float* __restrict__ counts,
                                   int E) {
    int i = blockIdx.x * blockDim.x + threadIdx.x;
    int total = E * DV;
    if (i >= total) return;
    int e = i / DV;
    int c = i & (DV - 1);
    int idx = index[e];
    float4 v = reinterpret_cast<const float4*>(msg)[(size_t)e * DV + c];
    float* dst = out + (size_t)idx * D_DIM + c * 4;
    atomicAdd(dst + 0, v.x);
    atomicAdd(dst + 1, v.y);
    atomicAdd(dst + 2, v.z);
    atomicAdd(dst + 3, v.w);
    if (c == 0) atomicAdd(&counts[idx], 1.0f);
}

__global__ void divide_kernel(float* __restrict__ out,
                              const float* __restrict__ counts,
                              int N) {
    int i = blockIdx.x * blockDim.x + threadIdx.x;
    int total = N * DV;
    if (i >= total) return;
    int n = i / DV;
    float inv = 1.0f / fmaxf(counts[n], 1.0f);
    float4* p = reinterpret_cast<float4*>(out) + i;
    float4 v = *p;
    v.x *= inv; v.y *= inv; v.z *= inv; v.w *= inv;
    *p = v;
}

// ===================== launcher =====================

extern "C" void kernel_launch(void* const* d_in, const int* in_sizes, int n_in,
                              void* d_out, int out_size, void* d_ws, size_t ws_size,
                              hipStream_t stream) {
    const float* msg   = (const float*)d_in[0];
    const int*   index = (const int*)d_in[1];
    float* out = (float*)d_out;

    int E = in_sizes[0] / D_DIM;   // 500000
    int N = out_size / D_DIM;      // 50000

    int nb = (N + 255) / 256;      // scan blocks (196 for N=50000)

    // Tier P workspace: sorted rows + counts + off + base + blocksum
    size_t needP = (size_t)E * D_DIM * sizeof(float)
                 + (size_t)(3 * (size_t)N + nb + 16) * sizeof(int);
    // Tier G workspace: cursor + buckets
    size_t needG = (size_t)N * sizeof(int) + (size_t)N * CAP * sizeof(int);

    if (ws_size >= needP && nb <= 256) {
        float* sorted   = (float*)d_ws;
        int*   counts   = (int*)(sorted + (size_t)E * D_DIM);
        int*   off      = counts + N;
        int*   base     = off + N;
        int*   blocksum = base + N;

        // counts and off are adjacent: one memset clears both.
        (void)hipMemsetAsync(counts, 0, (size_t)2 * N * sizeof(int), stream);

        count_kernel<<<(E + 255) / 256, 256, 0, stream>>>(index, counts, E);
        scan_blocks_kernel<<<nb, 256, 0, stream>>>(counts, base, blocksum, N);
        scan_sums_kernel<<<1, 256, 0, stream>>>(blocksum, nb);
        scan_add_kernel<<<nb, 256, 0, stream>>>(base, blocksum, N);

        permute_kernel<<<4096, 256, 0, stream>>>(msg, index, base, off, sorted, E);

        int grid_r = (N * 64 + 255) / 256;   // one wave per node
        reduce_kernel<<<grid_r, 256, 0, stream>>>(sorted, counts, base, out, N);
    } else if (ws_size >= needG) {
        int* cursor = (int*)d_ws;
        int* bucket = cursor + N;

        (void)hipMemsetAsync(cursor, 0, (size_t)N * sizeof(int), stream);
        {
            int block = 256;
            int grid = (E + block - 1) / block;
            bucket_kernel<<<grid, block, 0, stream>>>(index, cursor, bucket, E);
        }
        {
            int block = 256;
            int nodes_per_block = block / 64;
            int grid = (N + nodes_per_block - 1) / nodes_per_block;
            gather_kernel<<<grid, block, 0, stream>>>(msg, cursor, bucket, out, N);
        }
    } else {
        float* counts = (float*)d_ws;
        (void)hipMemsetAsync(out, 0, (size_t)out_size * sizeof(float), stream);
        (void)hipMemsetAsync(counts, 0, (size_t)N * sizeof(float), stream);
        {
            int total = E * DV;
            int block = 256;
            int grid = (total + block - 1) / block;
            scatter_add_kernel<<<grid, block, 0, stream>>>(msg, index, out, counts, E);
        }
        {
            int total = N * DV;
            int block = 256;
            int grid = (total + block - 1) / block;
            divide_kernel<<<grid, block, 0, stream>>>(out, counts, N);
        }
    }
}